// Round 1
// baseline (891.532 us; speedup 1.0000x reference)
//
#include <hip/hip_runtime.h>
#include <cstdint>

#define NB 2
#define NPER 65536
#define NPTS (NB*NPER)
#define CDIM 128
#define SV 64
#define VOX (SV*SV*SV)
#define WCOLS 1217
#define WSTRIDE 1232   // padded row stride (multiple of 16 floats -> 64B-aligned rows)

// Padded Wh3 lives in a static device buffer (rewritten every call; deterministic).
__device__ __align__(16) float g_Wh3p[32*WSTRIDE];

__global__ __launch_bounds__(256) void pad_wh3_kernel(const float* __restrict__ Wh3){
    int idx = blockIdx.x*256 + threadIdx.x;
    if (idx < 32*WCOLS){
        int k = idx / WCOLS;
        int c = idx - k*WCOLS;
        g_Wh3p[k*WSTRIDE + c] = Wh3[idx];
    }
}

// c_plane [B][C=128][VOX] -> ct [B][VOX][C=128]
__global__ __launch_bounds__(256) void transpose_kernel(const float* __restrict__ in,
                                                        float* __restrict__ out){
    __shared__ float tile[128][33];
    const int blk = blockIdx.x;        // NB * (VOX/32) blocks
    const int b  = blk >> 13;          // VOX/32 = 8192
    const int v0 = (blk & 8191) << 5;  // *32
    const int tx = threadIdx.x & 31;
    const int ty = threadIdx.x >> 5;   // 0..7
    const float* ip = in + (size_t)b*128*VOX + v0;
    #pragma unroll
    for (int cc = 0; cc < 16; cc++){
        int c = cc*8 + ty;
        tile[c][tx] = ip[(size_t)c*VOX + tx];
    }
    __syncthreads();
    const int cx = threadIdx.x & 127;
    const int vy = threadIdx.x >> 7;   // 0..1
    float* op = out + ((size_t)b*VOX + v0)*128;
    #pragma unroll
    for (int vv = 0; vv < 16; vv++){
        int v = vv*2 + vy;
        op[(size_t)v*128 + cx] = tile[cx][v];
    }
}

// wave-per-point trilinear sample from channel-last ct; lane handles 2 channels
__global__ __launch_bounds__(256) void sample_kernel(const float* __restrict__ pcl_mem,
                                                     const float* __restrict__ ct,
                                                     float* __restrict__ feats){
    const int tid  = threadIdx.x;
    const int lane = tid & 63;
    const int p    = blockIdx.x*4 + (tid >> 6);
    const int b    = p >> 16;

    float v0 = pcl_mem[3*p+0], v1 = pcl_mem[3*p+1], v2 = pcl_mem[3*p+2];
    auto src = [](float v){
        float g = 2.0f*v/63.0f - 1.0f;
        g = fminf(fmaxf(g, -2.0f), 2.0f);
        float t = (g + 1.0f)*0.5f*63.0f;
        return fminf(fmaxf(t, 0.0f), 63.0f);
    };
    float ix = src(v0), iy = src(v1), iz = src(v2);
    float fx = floorf(ix), fy = floorf(iy), fz = floorf(iz);
    float wx = ix-fx, wy = iy-fy, wz = iz-fz;
    int x0 = min(max((int)fx,0),63); int x1 = min(x0+1,63);
    int y0 = min(max((int)fy,0),63); int y1 = min(y0+1,63);
    int z0 = min(max((int)fz,0),63); int z1 = min(z0+1,63);
    float wx0 = 1.f-wx, wy0 = 1.f-wy, wz0 = 1.f-wz;

    const float2* base = (const float2*)ct + (size_t)b*VOX*64 + lane;
    float ax = 0.f, ay = 0.f;
#define CORNER(zz,yy,xx,wgt) { \
        float2 cv = base[(size_t)(((zz)*64+(yy))*64+(xx))*64]; \
        float w_ = (wgt); \
        ax = fmaf(w_, cv.x, ax); ay = fmaf(w_, cv.y, ay); }
    CORNER(z0,y0,x0, wz0*wy0*wx0);
    CORNER(z0,y0,x1, wz0*wy0*wx );
    CORNER(z0,y1,x0, wz0*wy *wx0);
    CORNER(z0,y1,x1, wz0*wy *wx );
    CORNER(z1,y0,x0, wz *wy0*wx0);
    CORNER(z1,y0,x1, wz *wy0*wx );
    CORNER(z1,y1,x0, wz *wy *wx0);
    CORNER(z1,y1,x1, wz *wy *wx );
#undef CORNER
    ((float2*)(feats + (size_t)p*CDIM))[lane] = make_float2(ax, ay);
}

// fallback (ws too small): thread per (point, channel), original layout
__global__ __launch_bounds__(256) void sample_slow_kernel(const float* __restrict__ pcl_mem,
                                                          const float* __restrict__ cpl,
                                                          float* __restrict__ feats){
    int gid = blockIdx.x*256 + threadIdx.x;   // p*128 + c
    int p = gid >> 7; int c = gid & 127;
    int b = p >> 16;
    float v0 = pcl_mem[3*p+0], v1 = pcl_mem[3*p+1], v2 = pcl_mem[3*p+2];
    auto src = [](float v){
        float g = 2.0f*v/63.0f - 1.0f;
        g = fminf(fmaxf(g, -2.0f), 2.0f);
        float t = (g + 1.0f)*0.5f*63.0f;
        return fminf(fmaxf(t, 0.0f), 63.0f);
    };
    float ix = src(v0), iy = src(v1), iz = src(v2);
    float fx = floorf(ix), fy = floorf(iy), fz = floorf(iz);
    float wx = ix-fx, wy = iy-fy, wz = iz-fz;
    int x0 = min(max((int)fx,0),63); int x1 = min(x0+1,63);
    int y0 = min(max((int)fy,0),63); int y1 = min(y0+1,63);
    int z0 = min(max((int)fz,0),63); int z1 = min(z0+1,63);
    float wx0 = 1.f-wx, wy0 = 1.f-wy, wz0 = 1.f-wz;
    const float* base = cpl + ((size_t)(b*128 + c))*VOX;
    float acc = 0.f;
    acc = fmaf(wz0*wy0*wx0, base[(z0*64+y0)*64+x0], acc);
    acc = fmaf(wz0*wy0*wx , base[(z0*64+y0)*64+x1], acc);
    acc = fmaf(wz0*wy *wx0, base[(z0*64+y1)*64+x0], acc);
    acc = fmaf(wz0*wy *wx , base[(z0*64+y1)*64+x1], acc);
    acc = fmaf(wz *wy0*wx0, base[(z1*64+y0)*64+x0], acc);
    acc = fmaf(wz *wy0*wx , base[(z1*64+y0)*64+x1], acc);
    acc = fmaf(wz *wy *wx0, base[(z1*64+y1)*64+x0], acc);
    acc = fmaf(wz *wy *wx , base[(z1*64+y1)*64+x1], acc);
    feats[gid] = acc;
}

__device__ __forceinline__ void fma4(float (&acc)[32], int jv, float s, float4 w){
    acc[4*jv+0] = fmaf(s, w.x, acc[4*jv+0]);
    acc[4*jv+1] = fmaf(s, w.y, acc[4*jv+1]);
    acc[4*jv+2] = fmaf(s, w.z, acc[4*jv+2]);
    acc[4*jv+3] = fmaf(s, w.w, acc[4*jv+3]);
}

// thread-per-point fused MLP + hypernetwork (hw never materialized)
__global__ __launch_bounds__(256) void mlp_kernel(
        const float* __restrict__ pcl_mem,
        const float* __restrict__ Wh1, const float* __restrict__ bh1,
        const float* __restrict__ Wh2, const float* __restrict__ bh2,
        const float* __restrict__ bh3,
        const float* __restrict__ feats,
        float* __restrict__ outp)
{
    __shared__ float lds_a[32][256];   // h1a, later a1 (each thread uses only its own column)
    __shared__ float lds_h[32][256];   // h2a for rolled-k loops
    const int tid = threadIdx.x;
    const int p   = blockIdx.x*256 + tid;

    float xv0, xv1, xv2;
    {
        float v0 = pcl_mem[3*p+0], v1 = pcl_mem[3*p+1], v2 = pcl_mem[3*p+2];
        xv0 = v0 - truncf(v0) - 0.5f;
        xv1 = v1 - truncf(v1) - 0.5f;
        xv2 = v2 - truncf(v2) - 0.5f;
    }

    const float4* f4  = (const float4*)(feats + (size_t)p*CDIM);
    const float4* W1q = (const float4*)Wh1;
    const float4* W2q = (const float4*)Wh2;
    const float4* W3q = (const float4*)g_Wh3p;
    const float4* b1q = (const float4*)bh1;
    const float4* b2q = (const float4*)bh2;
    const float4* b3q = (const float4*)bh3;
    const int RS = WSTRIDE/4;   // 308 float4 per Wh3p row

    // ---- h1 = leaky(feats @ Wh1 + bh1) ----
    float h1[32];
    #pragma unroll
    for (int jv=0;jv<8;jv++){ float4 bv=b1q[jv]; h1[4*jv]=bv.x; h1[4*jv+1]=bv.y; h1[4*jv+2]=bv.z; h1[4*jv+3]=bv.w; }
    for (int c4=0;c4<32;c4++){
        float4 f = f4[c4];
        float fs[4] = {f.x, f.y, f.z, f.w};
        #pragma unroll
        for (int cc=0;cc<4;cc++){
            #pragma unroll
            for (int jv=0;jv<8;jv++)
                fma4(h1, jv, fs[cc], W1q[(c4*4+cc)*8 + jv]);
        }
    }
    #pragma unroll
    for (int j=0;j<32;j++){ float a=h1[j]; lds_a[j][tid] = fmaxf(a, 0.01f*a); }

    // ---- h2 = leaky(h1a @ Wh2 + bh2) ----
    float h2[32];
    #pragma unroll
    for (int kv=0;kv<8;kv++){ float4 bv=b2q[kv]; h2[4*kv]=bv.x; h2[4*kv+1]=bv.y; h2[4*kv+2]=bv.z; h2[4*kv+3]=bv.w; }
    for (int j=0;j<32;j++){
        float aj = lds_a[j][tid];
        #pragma unroll
        for (int kv=0;kv<8;kv++) fma4(h2, kv, aj, W2q[j*8+kv]);
    }
    float h2a[32];
    #pragma unroll
    for (int k=0;k<32;k++){ float a=h2[k]; a = fmaxf(a, 0.01f*a); h2a[k]=a; lds_h[k][tid]=a; }

    // ---- o1[j] = x . W1[:, j] + b1[j], fused: hw cols 0..127 ----
    float o1[32];
    #pragma unroll
    for (int jv=0;jv<8;jv++){
        float4 ba=b3q[jv], bb=b3q[8+jv], bc=b3q[16+jv], bd=b3q[24+jv];
        o1[4*jv+0] = fmaf(xv0,ba.x, fmaf(xv1,bb.x, fmaf(xv2,bc.x, bd.x)));
        o1[4*jv+1] = fmaf(xv0,ba.y, fmaf(xv1,bb.y, fmaf(xv2,bc.y, bd.y)));
        o1[4*jv+2] = fmaf(xv0,ba.z, fmaf(xv1,bb.z, fmaf(xv2,bc.z, bd.z)));
        o1[4*jv+3] = fmaf(xv0,ba.w, fmaf(xv1,bb.w, fmaf(xv2,bc.w, bd.w)));
    }
    for (int k=0;k<32;k++){
        float hk = lds_h[k][tid];
        const float4* row = W3q + k*RS;
        #pragma unroll
        for (int jv=0;jv<8;jv++){
            float4 wa=row[jv], wb=row[8+jv], wc=row[16+jv], wd=row[24+jv];
            float m0 = fmaf(xv0,wa.x, fmaf(xv1,wb.x, fmaf(xv2,wc.x, wd.x)));
            float m1 = fmaf(xv0,wa.y, fmaf(xv1,wb.y, fmaf(xv2,wc.y, wd.y)));
            float m2 = fmaf(xv0,wa.z, fmaf(xv1,wb.z, fmaf(xv2,wc.z, wd.z)));
            float m3 = fmaf(xv0,wa.w, fmaf(xv1,wb.w, fmaf(xv2,wc.w, wd.w)));
            o1[4*jv+0] = fmaf(hk, m0, o1[4*jv+0]);
            o1[4*jv+1] = fmaf(hk, m1, o1[4*jv+1]);
            o1[4*jv+2] = fmaf(hk, m2, o1[4*jv+2]);
            o1[4*jv+3] = fmaf(hk, m3, o1[4*jv+3]);
        }
    }
    #pragma unroll
    for (int j=0;j<32;j++){ float a=o1[j]; lds_a[j][tid] = fmaxf(a, 0.01f*a); }  // a1

    // ---- o2 init = b2' = hw cols 1152..1183 ----
    float o2[32];
    #pragma unroll
    for (int jv=0;jv<8;jv++){ float4 bv=b3q[288+jv]; o2[4*jv]=bv.x; o2[4*jv+1]=bv.y; o2[4*jv+2]=bv.z; o2[4*jv+3]=bv.w; }
    for (int k=0;k<32;k++){
        float hk = lds_h[k][tid];
        const float4* row = W3q + k*RS + 288;
        #pragma unroll
        for (int jv=0;jv<8;jv++) fma4(o2, jv, hk, row[jv]);
    }

    // ---- main contraction: o2[j] += sum_i a1[i] * (bh3 + h2.Wh3)[128+i*32+j] ----
    for (int i=0;i<32;i++){
        float ai = lds_a[i][tid];
        float w2[32];
        #pragma unroll
        for (int jv=0;jv<8;jv++){ float4 bv=b3q[32+i*8+jv]; w2[4*jv]=bv.x; w2[4*jv+1]=bv.y; w2[4*jv+2]=bv.z; w2[4*jv+3]=bv.w; }
        #pragma unroll
        for (int k=0;k<32;k++){
            const float4* row = W3q + k*RS + 32 + i*8;
            #pragma unroll
            for (int jv=0;jv<8;jv++) fma4(w2, jv, h2a[k], row[jv]);
        }
        #pragma unroll
        for (int j=0;j<32;j++) o2[j] = fmaf(ai, w2[j], o2[j]);
    }

    // ---- final: o3 = leaky(o2) . W3' + b3' (hw cols 1184..1216) ----
    float w3[32];
    #pragma unroll
    for (int jv=0;jv<8;jv++){ float4 bv=b3q[296+jv]; w3[4*jv]=bv.x; w3[4*jv+1]=bv.y; w3[4*jv+2]=bv.z; w3[4*jv+3]=bv.w; }
    float o3 = bh3[1216];
    for (int k=0;k<32;k++){
        float hk = lds_h[k][tid];
        const float4* row = W3q + k*RS + 296;
        #pragma unroll
        for (int jv=0;jv<8;jv++) fma4(w3, jv, hk, row[jv]);
        o3 = fmaf(hk, g_Wh3p[k*WSTRIDE + 1216], o3);
    }
    #pragma unroll
    for (int j=0;j<32;j++){ float a=o2[j]; a = fmaxf(a, 0.01f*a); o3 = fmaf(a, w3[j], o3); }

    outp[p] = o3;
}

extern "C" void kernel_launch(void* const* d_in, const int* in_sizes, int n_in,
                              void* d_out, int out_size, void* d_ws, size_t ws_size,
                              hipStream_t stream)
{
    const float* pcl_mem = (const float*)d_in[1];
    const float* c_plane = (const float*)d_in[2];
    const float* Wh1     = (const float*)d_in[3];
    const float* bh1     = (const float*)d_in[4];
    const float* Wh2     = (const float*)d_in[5];
    const float* bh2     = (const float*)d_in[6];
    const float* Wh3     = (const float*)d_in[7];
    const float* bh3     = (const float*)d_in[8];
    float* outp  = (float*)d_out;
    float* feats = outp + NPTS;

    pad_wh3_kernel<<<(32*WCOLS+255)/256, 256, 0, stream>>>(Wh3);

    const size_t ct_bytes = (size_t)NB*VOX*CDIM*sizeof(float);   // 256 MiB
    if (ws_size >= ct_bytes) {
        float* ct = (float*)d_ws;
        transpose_kernel<<<NB*(VOX/32), 256, 0, stream>>>(c_plane, ct);
        sample_kernel<<<NPTS/4, 256, 0, stream>>>(pcl_mem, ct, feats);
    } else {
        sample_slow_kernel<<<(NPTS*CDIM)/256, 256, 0, stream>>>(pcl_mem, c_plane, feats);
    }

    mlp_kernel<<<NPTS/256, 256, 0, stream>>>(pcl_mem, Wh1, bh1, Wh2, bh2, bh3, feats, outp);
}